// Round 4
// baseline (4121.725 us; speedup 1.0000x reference)
//
#include <hip/hip_runtime.h>
#include <cstdint>

#define BB 128
#define SS 1024
#define HH 256
#define GG 768
#define DD 64                      // ring depth (power of 2)
#define LOG2E 1.44269504088896340736f

typedef __attribute__((ext_vector_type(8))) __bf16 bf16x8;
typedef __attribute__((ext_vector_type(4))) __bf16 bf16x4;
typedef __attribute__((ext_vector_type(4))) float f32x4;
typedef unsigned long long u64;

static __device__ __forceinline__ f32x4 mfma16(bf16x8 a, bf16x8 b, f32x4 c) {
    return __builtin_amdgcn_mfma_f32_16x16x32_bf16(a, b, c, 0, 0, 0);
}

static __device__ __forceinline__ bf16x8 load_w8(const float* __restrict__ p) {
    f32x4 a = *(const f32x4*)p;
    f32x4 b = *(const f32x4*)(p + 4);
    bf16x8 v;
    v[0] = (__bf16)a[0]; v[1] = (__bf16)a[1]; v[2] = (__bf16)a[2]; v[3] = (__bf16)a[3];
    v[4] = (__bf16)b[0]; v[5] = (__bf16)b[1]; v[6] = (__bf16)b[2]; v[7] = (__bf16)b[3];
    return v;
}

// LDS-only barrier (global stores keep floating) / full-drain barrier
#define LBAR() asm volatile("s_waitcnt lgkmcnt(0)\n\ts_barrier" ::: "memory")
#define VBAR() asm volatile("s_waitcnt vmcnt(0) lgkmcnt(0)\n\ts_barrier" ::: "memory")

// coherence-point (agent/sc1) 8-byte payload ops: no fences needed anywhere.
static __device__ __forceinline__ void st8(u64* p, u64 v) {
    __hip_atomic_store(p, v, __ATOMIC_RELAXED, __HIP_MEMORY_SCOPE_AGENT);
}
static __device__ __forceinline__ u64 ld8(const u64* p) {
    return __hip_atomic_load(p, __ATOMIC_RELAXED, __HIP_MEMORY_SCOPE_AGENT);
}

// ring element offset: slot-major, tile T=0..47, 8 batches x 16 outs
static __device__ __forceinline__ size_t ring_off(int t, int g, int T, int b8, int o) {
    return (((size_t)(t & (DD - 1)) * 16 + g) * 48 + T) * 128 + b8 * 16 + o;
}

// spin until *p >= need. Relaxed polls only; payload moves via sc1 atomics,
// ordering via producer-side vmcnt-drain-then-store. No fences.
static __device__ __forceinline__ int wait_ge(int* p, int need) {
    int v = __hip_atomic_load(p, __ATOMIC_RELAXED, __HIP_MEMORY_SCOPE_AGENT);
    while (v < need) {
        __builtin_amdgcn_s_sleep(2);
        v = __hip_atomic_load(p, __ATOMIC_RELAXED, __HIP_MEMORY_SCOPE_AGENT);
    }
    return v;
}

static __device__ __forceinline__ void publish(int* p, int v) {
    __hip_atomic_store(p, v, __ATOMIC_RELAXED, __HIP_MEMORY_SCOPE_AGENT);
}

// load the 48 W-tiles for this WG: wave w holds tiles w+8j, j=0..3 in VGPR,
// j=4,5 staged to LDS (16B/lane frags)
static __device__ __forceinline__ void load_wfrags(
    const float* __restrict__ W, char* wlds, bf16x8 (&wf)[4][8],
    int w, int l, int c, int q)
{
#pragma unroll
    for (int j = 0; j < 4; ++j) {
        const float* wp = W + (size_t)((w + 8 * j) * 16 + c) * HH + q * 8;
#pragma unroll
        for (int kf = 0; kf < 8; ++kf) wf[j][kf] = load_w8(wp + kf * 32);
    }
#pragma unroll
    for (int j = 4; j < 6; ++j) {
        const float* wp = W + (size_t)((w + 8 * j) * 16 + c) * HH + q * 8;
#pragma unroll
        for (int kf = 0; kf < 8; ++kf) {
            bf16x8 v = load_w8(wp + kf * 32);
            *(bf16x8*)(wlds + (((w * 2 + (j - 4)) * 8 + kf) << 10) + l * 16) = v;
        }
    }
}

// 768x8(x16-padded) GEMM: 48 MFMAs/wave over K=256 from a swizzled LDS
// B-buffer (8 rows x 256 bf16, row stride 512B, byte ^= (row&7)<<4)
static __device__ __forceinline__ void gemm6(
    f32x4 (&acc)[6], const char* bsrc, const char* wlds,
    const bf16x8 (&wf)[4][8], int w, int l, int q, int b8)
{
#pragma unroll
    for (int kh = 0; kh < 2; ++kh) {
        bf16x8 hb[4];
#pragma unroll
        for (int kf = 0; kf < 4; ++kf) {
            int k0 = kh * 128 + kf * 32 + q * 8;
            hb[kf] = *(const bf16x8*)(bsrc + b8 * 512 + ((2 * k0) ^ (b8 << 4)));
        }
#pragma unroll
        for (int j = 0; j < 4; ++j)
#pragma unroll
            for (int kf = 0; kf < 4; ++kf)
                acc[j] = mfma16(wf[j][kh * 4 + kf], hb[kf], acc[j]);
#pragma unroll
        for (int j = 4; j < 6; ++j)
#pragma unroll
            for (int kf = 0; kf < 4; ++kf) {
                bf16x8 a = *(const bf16x8*)(wlds +
                    (((w * 2 + (j - 4)) * 8 + kh * 4 + kf) << 10) + l * 16);
                acc[j] = mfma16(a, hb[kf], acc[j]);
            }
    }
}

// ---------------------------------------------------------------------------
// Fused 4-stage pipeline. 64 WGs x 512 thr: role = bid>>4, g = bid&15.
//   role 0: L0ih (x -> ring0)        role 1: L0rec (ring0 -> Y=h0 via sc1)
//   role 2: L1ih (Y=h0 -> ring1)     role 3: L1rec (ring1 -> Y=h1 plain)
// All cross-stage payload moves via relaxed agent (sc1/LLC) u64 atomics;
// flags are relaxed atomics ordered by producer-side VBAR. Zero fences.
// ---------------------------------------------------------------------------
__global__ __launch_bounds__(512, 2) void k_fused(
    const float* __restrict__ x, const float* __restrict__ hx,
    const float* __restrict__ W_ih, const float* __restrict__ W_hh,
    const float* __restrict__ gamma, const float* __restrict__ beta,
    float* __restrict__ Y, char* __restrict__ ws)
{
    extern __shared__ __align__(16) char lds[];
    const int bid = blockIdx.x;
    const int role = bid >> 4;
    const int g = bid & 15;
    const int layer = role >> 1;

    __bf16* ring0 = (__bf16*)ws;
    __bf16* ring1 = (__bf16*)(ws + (64u << 20));
    int* flagbase = (int*)(ws + (128u << 20));
#define FLAG(kind, gg) (flagbase + ((kind) * 16 + (gg)) * 32)

    const int tid = threadIdx.x;
    const int w = tid >> 6, l = tid & 63;
    const int c = l & 15, q = l >> 4;
    const int b8 = c & 7, chi = c >> 3;

    char* wlds = lds;                        // 131072 B: W tiles j=4,5

    if (!(role & 1)) {
        // ================= ih stage =================
        char* xst = lds + 131072;            // 2 x 4096: input[8][256] bf16 swz
        const float* in = layer ? (const float*)Y : x;
        const float* W = W_ih + (size_t)layer * GG * HH;
        __bf16* ring = layer ? ring1 : ring0;
        int* p_self = FLAG(layer ? 2 : 0, g);
        int* p_dep  = layer ? FLAG(1, g) : nullptr;
        int* p_bp   = FLAG(layer ? 3 : 1, g);

        bf16x8 wf[4][8];
        load_wfrags(W, wlds, wf, w, l, c, q);
        __syncthreads();

        const int stb = tid >> 6;            // staging: batch 0..7
        const int stk = (tid & 63) * 4;      // k offset 0..252
        int kd = 0, kc = 0;

#pragma unroll 1
        for (int t = 0; t < SS; ++t) {
            if (t >= DD && kc < t - DD + 1) kc = wait_ge(p_bp, t - DD + 1);
            if (p_dep && kd < t + 1) kd = wait_ge(p_dep, t + 1);
            {
                const float* sp = in + ((size_t)(g * 8 + stb) * SS + t) * HH + stk;
                f32x4 v;
                if (layer) {
                    // h0 handoff: read at coherence point
                    u64 a0 = ld8((const u64*)sp);
                    u64 a1 = ld8((const u64*)sp + 1);
                    float2 f0 = __builtin_bit_cast(float2, a0);
                    float2 f1 = __builtin_bit_cast(float2, a1);
                    v = (f32x4){f0.x, f0.y, f1.x, f1.y};
                } else {
                    v = *(const f32x4*)sp;
                }
                bf16x4 o;
#pragma unroll
                for (int r = 0; r < 4; ++r) o[r] = (__bf16)v[r];
                *(bf16x4*)(xst + (t & 1) * 4096 + stb * 512 +
                           ((2 * stk) ^ ((stb & 7) << 4))) = o;
            }
            LBAR();
            f32x4 acc[6];
#pragma unroll
            for (int j = 0; j < 6; ++j) acc[j] = (f32x4){0.f, 0.f, 0.f, 0.f};
            gemm6(acc, xst + (t & 1) * 4096, wlds, wf, w, l, q, b8);
            if (c < 8) {
                size_t base = ring_off(t, g, 0, b8, q * 4);
#pragma unroll
                for (int j = 0; j < 6; ++j) {
                    bf16x4 o;
#pragma unroll
                    for (int r = 0; r < 4; ++r) o[r] = (__bf16)acc[j][r];
                    st8((u64*)(ring + base + (size_t)(w + 8 * j) * 128),
                        __builtin_bit_cast(u64, o));
                }
            }
            VBAR();  // all waves' ring stores ack'd at LLC before flag
            if (tid == 0) publish(p_self, t + 1);
        }
    } else {
        // ================= rec stage =================
        char*  hbuf = lds + 131072;          // 4096: h[8][256] bf16 swz
        float* part = (float*)(lds + 135168);// 3 gates x 8 b x 20 floats
        float* gb   = (float*)(lds + 137088);// 6144: prescaled gamma|beta

        const __bf16* ring = layer ? ring1 : ring0;
        const float* Whh = W_hh + (size_t)layer * GG * HH;
        const float* gmm = gamma + (size_t)layer * GG;
        const float* bta = beta + (size_t)layer * GG;
        const float* hx0 = hx + (size_t)layer * BB * HH;
        int* p_src  = FLAG(layer ? 2 : 0, g);
        int* p_self = FLAG(layer ? 3 : 1, g);

        for (int idx = tid; idx < GG; idx += 512) {
            float sc = (idx >= 512) ? (-2.0f * LOG2E) : (-LOG2E);
            gb[idx]      = gmm[idx] * sc;
            gb[GG + idx] = bta[idx] * sc;
        }
        for (int idx = tid; idx < 8 * HH; idx += 512) {
            int b = idx >> 8, k = idx & 255;
            *(__bf16*)(hbuf + b * 512 + ((2 * k) ^ ((b & 7) << 4))) =
                (__bf16)hx0[(size_t)(g * 8 + b) * HH + k];
        }
        bf16x8 wf[4][8];
        load_wfrags(Whh, wlds, wf, w, l, c, q);
        __syncthreads();

        const int o0base = (w + 8 * chi) * 16 + q * 4;
        const int ho = w * 16 + chi * 128 + q * 4;
        float* yb = Y + (size_t)(g * 8 + b8) * SS * HH;

        int kp = wait_ge(p_src, 1);
        bf16x4 ihc[3], ihn[3];
        {
            size_t base = ring_off(0, g, 0, b8, q * 4);
#pragma unroll
            for (int j2 = 0; j2 < 3; ++j2)
                ihc[j2] = __builtin_bit_cast(bf16x4, ld8(
                    (const u64*)(ring + base + (size_t)(w + 8 * chi + 16 * j2) * 128)));
        }

#pragma unroll 1
        for (int t = 0; t < SS; ++t) {
            int need = (t + 2 < SS) ? t + 2 : SS;
            if (kp < need) kp = wait_ge(p_src, need);
            {
                int tn = (t + 1 < SS) ? t + 1 : t;
                size_t base = ring_off(tn, g, 0, b8, q * 4);
#pragma unroll
                for (int j2 = 0; j2 < 3; ++j2)
                    ihn[j2] = __builtin_bit_cast(bf16x4, ld8(
                        (const u64*)(ring + base + (size_t)(w + 8 * chi + 16 * j2) * 128)));
            }

            f32x4 acc[6];
#pragma unroll
            for (int j = 0; j < 6; ++j) acc[j] = (f32x4){0.f, 0.f, 0.f, 0.f};
            gemm6(acc, hbuf, wlds, wf, w, l, q, b8);

            // lane's tiles: w+8chi+16j2; B-cols c and c^8 duplicate, so the
            // odd-tile values for chi=1 lanes are already in acc[2j2+1].
            f32x4 pa[3];
#pragma unroll
            for (int j2 = 0; j2 < 3; ++j2)
                pa[j2] = chi ? acc[2 * j2 + 1] : acc[2 * j2];

            // r,z stats
            float s0 = 0.f, t0 = 0.f, s1 = 0.f, t1 = 0.f;
#pragma unroll
            for (int r = 0; r < 4; ++r) {
                float p0 = pa[0][r] + (float)ihc[0][r]; pa[0][r] = p0; s0 += p0; t0 += p0 * p0;
                float p1 = pa[1][r] + (float)ihc[1][r]; pa[1][r] = p1; s1 += p1; t1 += p1 * p1;
            }
            s0 += __shfl_xor(s0, 16); t0 += __shfl_xor(t0, 16);
            s0 += __shfl_xor(s0, 32); t0 += __shfl_xor(t0, 32);
            s0 += __shfl_xor(s0, 8);  t0 += __shfl_xor(t0, 8);
            s1 += __shfl_xor(s1, 16); t1 += __shfl_xor(t1, 16);
            s1 += __shfl_xor(s1, 32); t1 += __shfl_xor(t1, 32);
            s1 += __shfl_xor(s1, 8);  t1 += __shfl_xor(t1, 8);
            if (l < 8) {
                *(float2*)(part + (0 * 8 + l) * 20 + w * 2) = make_float2(s0, t0);
                *(float2*)(part + (1 * 8 + l) * 20 + w * 2) = make_float2(s1, t1);
            }
            LBAR();  // BAR1

            float2 mrz[2];
#pragma unroll
            for (int gg = 0; gg < 2; ++gg) {
                const f32x4* pp = (const f32x4*)(part + (gg * 8 + b8) * 20);
                f32x4 a = pp[0] + pp[1] + pp[2] + pp[3];
                float S = a[0] + a[2], Q2 = a[1] + a[3];
                float m = S * (1.f / 256.f);
                float v = Q2 * (1.f / 256.f) - m * m;
                mrz[gg] = make_float2(m, __builtin_amdgcn_rsqf(v + 1e-5f));
            }

            float rz[2][4];
#pragma unroll
            for (int gg = 0; gg < 2; ++gg) {
                int o0 = o0base + gg * 256;
                f32x4 gam = *(f32x4*)(gb + o0);
                f32x4 bet = *(f32x4*)(gb + GG + o0);
#pragma unroll
                for (int r = 0; r < 4; ++r) {
                    float sf = mrz[gg].y * gam[r];
                    float y  = pa[gg][r] * sf + (bet[r] - mrz[gg].x * sf);
                    rz[gg][r] = __builtin_amdgcn_rcpf(1.f + __builtin_amdgcn_exp2f(y));
                }
            }

            float pn[4]; float sn = 0.f, tn2 = 0.f;
#pragma unroll
            for (int r = 0; r < 4; ++r) {
                float p = (float)ihc[2][r] + rz[0][r] * pa[2][r];
                pn[r] = p; sn += p; tn2 += p * p;
            }
            sn += __shfl_xor(sn, 16); tn2 += __shfl_xor(tn2, 16);
            sn += __shfl_xor(sn, 32); tn2 += __shfl_xor(tn2, 32);
            sn += __shfl_xor(sn, 8);  tn2 += __shfl_xor(tn2, 8);
            if (l < 8)
                *(float2*)(part + (2 * 8 + l) * 20 + w * 2) = make_float2(sn, tn2);
            LBAR();  // BAR2

            {
                const f32x4* pp = (const f32x4*)(part + (2 * 8 + b8) * 20);
                f32x4 a = pp[0] + pp[1] + pp[2] + pp[3];
                float S = a[0] + a[2], Q2 = a[1] + a[3];
                float m = S * (1.f / 256.f);
                float v = Q2 * (1.f / 256.f) - m * m;
                float rs = __builtin_amdgcn_rsqf(v + 1e-5f);

                int o0 = o0base + 512;
                f32x4 gam = *(f32x4*)(gb + o0);
                f32x4 bet = *(f32x4*)(gb + GG + o0);
                char* haddr = hbuf + b8 * 512 + ((2 * ho) ^ (b8 << 4));
                bf16x4 hov = *(bf16x4*)haddr;
                f32x4 yv; bf16x4 hnv;
#pragma unroll
                for (int r = 0; r < 4; ++r) {
                    float sf = rs * gam[r];
                    float y  = pn[r] * sf + (bet[r] - m * sf);
                    float nh = 2.f * __builtin_amdgcn_rcpf(1.f + __builtin_amdgcn_exp2f(y)) - 1.f;
                    float hn = nh + rz[1][r] * ((float)hov[r] - nh);
                    yv[r] = hn; hnv[r] = (__bf16)hn;
                }
                *(bf16x4*)haddr = hnv;
                float* yp = yb + (size_t)t * HH + ho;
                if (layer == 0) {
                    // h0 handoff to L1ih: store at coherence point
                    float2 lo = make_float2(yv[0], yv[1]);
                    float2 hi = make_float2(yv[2], yv[3]);
                    st8((u64*)yp,     __builtin_bit_cast(u64, lo));
                    st8((u64*)yp + 1, __builtin_bit_cast(u64, hi));
                } else {
                    *(f32x4*)yp = yv;   // final output, plain store
                }
            }
#pragma unroll
            for (int j2 = 0; j2 < 3; ++j2) ihc[j2] = ihn[j2];

            if ((t & 1) == 1) {
                VBAR();  // drain Y/ring-consumer loads + h0 stores, then flag
                if (tid == 0) publish(p_self, t + 1);
            } else {
                LBAR();  // BAR3
            }
        }
    }
#undef FLAG
}

// ---------------------------------------------------------------------------
extern "C" void kernel_launch(void* const* d_in, const int* in_sizes, int n_in,
                              void* d_out, int out_size, void* d_ws, size_t ws_size,
                              hipStream_t stream)
{
    (void)in_sizes; (void)n_in; (void)out_size;
    const float* x    = (const float*)d_in[0];
    const float* hx   = (const float*)d_in[1];
    const float* W_ih = (const float*)d_in[2];
    const float* W_hh = (const float*)d_in[3];
    const float* gmm  = (const float*)d_in[4];
    const float* bta  = (const float*)d_in[5];
    float* Y = (float*)d_out;
    char* ws = (char*)d_ws;

    // ws usage: ring0 [0,12.6MB) ring1 [64MiB,+12.6MB) flags [128MiB,+8KB)
    if (ws_size < (size_t)SS * BB * GG * 2) return;

    hipFuncSetAttribute((const void*)k_fused,
                        hipFuncAttributeMaxDynamicSharedMemorySize, 143232);

    // zero the progress flags (re-zeroed on every replay)
    hipMemsetAsync(ws + (128u << 20), 0, 64 * 32 * 4, stream);

    k_fused<<<dim3(64), dim3(512), 143232, stream>>>(
        x, hx, W_ih, W_hh, gmm, bta, Y, ws);
}